// Round 6
// baseline (285.076 us; speedup 1.0000x reference)
//
#include <hip/hip_runtime.h>

typedef __bf16 bf16;
typedef bf16 bf16x4 __attribute__((ext_vector_type(4)));
typedef bf16 bf16x8 __attribute__((ext_vector_type(8)));
typedef float f32x4 __attribute__((ext_vector_type(4)));

#define CH 256
#define HH 56
#define WW 56
#define HW 3136
#define MM 12544
#define KT 2304

__device__ __forceinline__ void gll16(const bf16* g, bf16* l) {
  __builtin_amdgcn_global_load_lds(
      (const __attribute__((address_space(1))) void*)g,
      (__attribute__((address_space(3))) void*)l, 16, 0, 0);
}

// ---------------- NCHW fp32 -> NHWC bf16 ----------------
__global__ __launch_bounds__(256) void nchw2nhwc_k(const float* __restrict__ x,
                                                   bf16* __restrict__ o) {
  __shared__ float t[32][33];
  const int b = blockIdx.z, hw0 = blockIdx.x * 32, c0 = blockIdx.y * 32;
  const int tid = threadIdx.x;
  {
    const int cl = tid >> 3, hwl = (tid & 7) * 4;
    f32x4 v = *(const f32x4*)&x[(size_t)(b * CH + c0 + cl) * HW + hw0 + hwl];
#pragma unroll
    for (int i = 0; i < 4; ++i) t[cl][hwl + i] = v[i];
  }
  __syncthreads();
  const int hwl = tid >> 3, cl = (tid & 7) * 4;
  bf16x4 ov;
#pragma unroll
  for (int i = 0; i < 4; ++i) ov[i] = (bf16)t[cl + i][hwl];
  *(bf16x4*)&o[(size_t)(b * HW + hw0 + hwl) * CH + c0 + cl] = ov;
}

// ---------------- weight reorder: [O][C][3][3] fp32 -> [Ntot][tap*256+c] bf16
__global__ void reorder_w_k(const float* __restrict__ in, bf16* __restrict__ out,
                            int Nsrc, int Ntot) {
  const int idx = blockIdx.x * 256 + threadIdx.x;
  if (idx >= Ntot * KT) return;
  const int o = idx / KT, r = idx - o * KT;
  const int k = r >> 8, c = r & 255;
  float v = (o < Nsrc) ? in[(size_t)(o * CH + c) * 9 + k] : 0.f;
  out[idx] = (bf16)v;
}

// ---------------- deform sample: contiguous-line writes, bias added here ------
__global__ __launch_bounds__(256) void build_deform_k(
    const bf16* __restrict__ xn, const float* __restrict__ offb,
    const float* __restrict__ boff, bf16* __restrict__ A1) {
  const int tid = threadIdx.x;
  const int m = blockIdx.x * 32 + (tid >> 3);
  const int l7 = tid & 7;
  const int b = m / HW, hw = m - b * HW;
  const int h = hw / WW, w = hw - h * WW;
  const float* orow = offb + m * 18;
  const bf16* xb = xn + (size_t)b * HW * CH;
  bf16* dst = A1 + (size_t)m * KT;
  for (int tap = 0; tap < 9; ++tap) {
    const int ky = tap / 3, kx = tap - ky * 3;
    const float dy = orow[2 * tap] + boff[2 * tap];
    const float dx = orow[2 * tap + 1] + boff[2 * tap + 1];
    const float py = (float)(h + ky * 2 - 2) + dy;
    const float px = (float)(w + kx * 2 - 2) + dx;
    const float y0f = floorf(py), x0f = floorf(px);
    const int y0 = (int)y0f, x0 = (int)x0f;
    const float wy = py - y0f, wx = px - x0f;
    const float w00 = (1.f - wy) * (1.f - wx), w01 = (1.f - wy) * wx;
    const float w10 = wy * (1.f - wx), w11 = wy * wx;
    const bool vy0 = (unsigned)y0 < HH, vy1 = (unsigned)(y0 + 1) < HH;
    const bool vx0 = (unsigned)x0 < WW, vx1 = (unsigned)(x0 + 1) < WW;
    const bf16* p00 = xb + (long long)(y0 * WW + x0) * CH;
#pragma unroll
    for (int j = 0; j < 4; ++j) {
      const int cc = j * 64 + l7 * 8;  // lanes 0..7 -> contiguous 128B line
      bf16x8 v00 = {}, v01 = {}, v10 = {}, v11 = {};
      if (vy0 && vx0) v00 = *(const bf16x8*)(p00 + cc);
      if (vy0 && vx1) v01 = *(const bf16x8*)(p00 + CH + cc);
      if (vy1 && vx0) v10 = *(const bf16x8*)(p00 + WW * CH + cc);
      if (vy1 && vx1) v11 = *(const bf16x8*)(p00 + WW * CH + CH + cc);
      bf16x8 o;
#pragma unroll
      for (int i = 0; i < 8; ++i)
        o[i] = (bf16)(w00 * (float)v00[i] + w01 * (float)v01[i] +
                      w10 * (float)v10[i] + w11 * (float)v11[i]);
      *(bf16x8*)(dst + tap * 256 + cc) = o;
    }
  }
}

// ---------------- offset conv GEMM: 64x64 tile, split-K=4, atomic 18-col epi --
__global__ __launch_bounds__(256, 3) void offset_gemm_k(
    const bf16* __restrict__ xn, const bf16* __restrict__ wof,
    const bf16* __restrict__ zp, float* __restrict__ offout) {
  __shared__ __align__(16) bf16 Ab[2][4096];
  __shared__ __align__(16) bf16 Bb[2][4096];
  const int tid = threadIdx.x;
  const int m0 = blockIdx.y * 64;
  const int kbase = blockIdx.z * 576;  // 9 ksteps of 64
  const int lane = tid & 63, wv = tid >> 6;
  const int wrM = wv >> 1, wcN = wv & 1;
  const int fr = lane & 15, kg = lane >> 4;
  const int srow = tid >> 3, cpos = tid & 7;
  const int sxor = (cpos ^ (srow & 7)) * 8;

  int bb[2], hh[2], wwv[2];
#pragma unroll
  for (int pa = 0; pa < 2; ++pa) {
    const int m = m0 + pa * 32 + srow;
    bb[pa] = m / HW;
    const int hw = m - bb[pa] * HW;
    hh[pa] = hw / WW;
    wwv[pa] = hw - hh[pa] * WW;
  }
  const bf16* bptr[2];
#pragma unroll
  for (int pb = 0; pb < 2; ++pb)
    bptr[pb] = wof + (size_t)(pb * 32 + srow) * KT + kbase + sxor;

  f32x4 acc[2][2] = {};

  auto STAGE = [&](int kt, int buf) {
    const int kk = kbase + kt * 64;
    const int tap = kk >> 8, coff = kk & 255;
    const int ky = tap / 3, kx = tap - ky * 3;
#pragma unroll
    for (int pa = 0; pa < 2; ++pa) {
      const int y = hh[pa] + ky * 2 - 2, xx = wwv[pa] + kx * 2 - 2;
      const bool ok = ((unsigned)y < HH) && ((unsigned)xx < WW);
      const bf16* as =
          ok ? xn + ((size_t)(bb[pa] * HW + y * WW + xx) * CH + coff + sxor)
             : zp + sxor;
      gll16(as, &Ab[buf][(pa * 32 + srow) * 64 + cpos * 8]);
    }
#pragma unroll
    for (int pb = 0; pb < 2; ++pb)
      gll16(bptr[pb] + kt * 64, &Bb[buf][(pb * 32 + srow) * 64 + cpos * 8]);
  };

  auto COMPUTE = [&](int buf) {
#pragma unroll
    for (int kh = 0; kh < 2; ++kh) {
      bf16x8 af[2], bv[2];
#pragma unroll
      for (int mf = 0; mf < 2; ++mf) {
        const int row = wrM * 32 + mf * 16 + fr;
        const int g = (kh * 4 + kg) ^ (row & 7);
        af[mf] = *(const bf16x8*)&Ab[buf][row * 64 + g * 8];
      }
#pragma unroll
      for (int nf = 0; nf < 2; ++nf) {
        const int row = wcN * 32 + nf * 16 + fr;
        const int g = (kh * 4 + kg) ^ (row & 7);
        bv[nf] = *(const bf16x8*)&Bb[buf][row * 64 + g * 8];
      }
#pragma unroll
      for (int mf = 0; mf < 2; ++mf)
#pragma unroll
        for (int nf = 0; nf < 2; ++nf)
          acc[mf][nf] = __builtin_amdgcn_mfma_f32_16x16x32_bf16(af[mf], bv[nf],
                                                                acc[mf][nf], 0, 0, 0);
    }
  };

  STAGE(0, 0);
  __syncthreads();
  int buf = 0;
  for (int kt = 0; kt < 9; ++kt) {
    if (kt + 1 < 9) STAGE(kt + 1, buf ^ 1);
    COMPUTE(buf);
    __syncthreads();
    buf ^= 1;
  }
#pragma unroll
  for (int mf = 0; mf < 2; ++mf) {
    const int rr = m0 + wrM * 32 + mf * 16 + kg * 4;
#pragma unroll
    for (int nf = 0; nf < 2; ++nf) {
      const int col = wcN * 32 + nf * 16 + fr;
      if (col < 18) {
#pragma unroll
        for (int r = 0; r < 4; ++r)
          atomicAdd(&offout[(size_t)(rr + r) * 18 + col], acc[mf][nf][r]);
      }
    }
  }
}

// ---------------- 128x128 GEMM, m97 structure, split-K, f32 atomic epilogue ---
// MODE 0: A linear k-major [m][KT].  MODE 1: A implicit im2col from NHWC bf16.
template <int MODE>
__global__ __launch_bounds__(256) void gemm128_k(
    const bf16* __restrict__ Asrc, const bf16* __restrict__ Bt,
    const bf16* __restrict__ zp, float* __restrict__ outp,
    const int dil, const int pad) {
  __shared__ __align__(16) bf16 Ab[128 * 64];
  __shared__ __align__(16) bf16 Bb[128 * 64];
  const int tid = threadIdx.x;
  const int n0 = blockIdx.x * 128, m0 = blockIdx.y * 128;
  const int kbase = blockIdx.z * 768;  // 12 ksteps of 64
  const int lane = tid & 63, wv = tid >> 6;
  const int wrM = wv >> 1, wcN = wv & 1;
  const int fr = lane & 15, kg = lane >> 4;
  const int srow = tid >> 3, cpos = tid & 7;
  const int sxor = (cpos ^ (srow & 7)) * 8;  // source-side swizzle (involution)

  int bb[4], hh[4], wwv[4];
  const bf16* aptr[4];
  if (MODE == 1) {
#pragma unroll
    for (int q = 0; q < 4; ++q) {
      const int m = m0 + q * 32 + srow;
      bb[q] = m / HW;
      const int hw = m - bb[q] * HW;
      hh[q] = hw / WW;
      wwv[q] = hw - hh[q] * WW;
    }
  } else {
#pragma unroll
    for (int q = 0; q < 4; ++q)
      aptr[q] = Asrc + (size_t)(m0 + q * 32 + srow) * KT + kbase + sxor;
  }
  const bf16* bptr[4];
#pragma unroll
  for (int q = 0; q < 4; ++q)
    bptr[q] = Bt + (size_t)(n0 + q * 32 + srow) * KT + kbase + sxor;

  f32x4 acc[4][4] = {};

  for (int kt = 0; kt < 12; ++kt) {
    const int kk = kbase + kt * 64;
    // STAGE (single buffer, m97 structure)
#pragma unroll
    for (int q = 0; q < 4; ++q) {
      const bf16* as;
      if (MODE == 0) {
        as = aptr[q] + kt * 64;
      } else {
        const int tap = kk >> 8, coff = kk & 255;
        const int ky = tap / 3, kx = tap - ky * 3;
        const int y = hh[q] + ky * dil - pad, xx = wwv[q] + kx * dil - pad;
        const bool ok = ((unsigned)y < HH) && ((unsigned)xx < WW);
        as = ok ? Asrc + ((size_t)(bb[q] * HW + y * WW + xx) * CH + coff + sxor)
                : zp + sxor;
      }
      gll16(as, &Ab[(q * 32 + srow) * 64 + cpos * 8]);
      gll16(bptr[q] + kt * 64, &Bb[(q * 32 + srow) * 64 + cpos * 8]);
    }
    __syncthreads();
    // COMPUTE: 32 MFMA
#pragma unroll
    for (int kh = 0; kh < 2; ++kh) {
      bf16x8 af[4], bv[4];
#pragma unroll
      for (int mf = 0; mf < 4; ++mf) {
        const int row = wrM * 64 + mf * 16 + fr;
        const int g = (kh * 4 + kg) ^ (row & 7);
        af[mf] = *(const bf16x8*)&Ab[row * 64 + g * 8];
      }
#pragma unroll
      for (int nf = 0; nf < 4; ++nf) {
        const int row = wcN * 64 + nf * 16 + fr;
        const int g = (kh * 4 + kg) ^ (row & 7);
        bv[nf] = *(const bf16x8*)&Bb[row * 64 + g * 8];
      }
#pragma unroll
      for (int mf = 0; mf < 4; ++mf)
#pragma unroll
        for (int nf = 0; nf < 4; ++nf)
          acc[mf][nf] = __builtin_amdgcn_mfma_f32_16x16x32_bf16(af[mf], bv[nf],
                                                                acc[mf][nf], 0, 0, 0);
    }
    __syncthreads();
  }

  // split-K epilogue: f32 atomic accumulate
#pragma unroll
  for (int mf = 0; mf < 4; ++mf) {
    const int rr = m0 + wrM * 64 + mf * 16 + kg * 4;
#pragma unroll
    for (int nf = 0; nf < 4; ++nf) {
      const int col = n0 + wcN * 64 + nf * 16 + fr;
#pragma unroll
      for (int r = 0; r < 4; ++r)
        atomicAdd(&outp[(size_t)(rr + r) * CH + col], acc[mf][nf][r]);
    }
  }
}

// ---------------- per-channel sum/sumsq over f32 [12544][256]
__global__ __launch_bounds__(256) void stats_f32(const float* __restrict__ d,
                                                 float* __restrict__ s,
                                                 float* __restrict__ sq) {
  const int c = threadIdx.x;
  const int m0 = blockIdx.x * 64;
  float a = 0.f, q = 0.f;
  for (int i = 0; i < 64; ++i) {
    float v = d[(size_t)(m0 + i) * CH + c];
    a += v;
    q += v * v;
  }
  atomicAdd(&s[c], a);
  atomicAdd(&sq[c], q);
}

__global__ void affine_k(const float* __restrict__ s, const float* __restrict__ sq,
                         const float* __restrict__ g, const float* __restrict__ be,
                         float* __restrict__ sc, float* __restrict__ bi) {
  const int c = threadIdx.x;
  const float inv = 1.f / (float)MM;
  const float mean = s[c] * inv;
  const float var = sq[c] * inv - mean * mean;
  const float scale = g[c] * rsqrtf(var + 1e-5f);
  sc[c] = scale;
  bi[c] = be[c] - mean * scale;
}

// ---------------- act = bf16(relu(in*scale+bias)), f32 in -> bf16 out
__global__ __launch_bounds__(256) void a1_f32(const float* __restrict__ in,
                                              const float* __restrict__ sc,
                                              const float* __restrict__ bi,
                                              bf16* __restrict__ out) {
  const size_t idx = (size_t)(blockIdx.x * 256 + threadIdx.x) * 8;
  const int c0 = (int)(idx & 255);
  f32x4 v0 = *(const f32x4*)&in[idx];
  f32x4 v1 = *(const f32x4*)&in[idx + 4];
  bf16x8 o;
#pragma unroll
  for (int i = 0; i < 4; ++i) {
    float r = v0[i] * sc[c0 + i] + bi[c0 + i];
    o[i] = (bf16)(r > 0.f ? r : 0.f);
  }
#pragma unroll
  for (int i = 0; i < 4; ++i) {
    float r = v1[i] * sc[c0 + 4 + i] + bi[c0 + 4 + i];
    o[4 + i] = (bf16)(r > 0.f ? r : 0.f);
  }
  *(bf16x8*)&out[idx] = o;
}

// ---------------- out = relu(o2*sc+bi + x), f32 NHWC -> f32 NCHW
__global__ __launch_bounds__(256) void final_f32(const float* __restrict__ o2,
                                                 const float* __restrict__ x,
                                                 const float* __restrict__ sc,
                                                 const float* __restrict__ bi,
                                                 float* __restrict__ out) {
  __shared__ float t[32][33];
  const int b = blockIdx.z, hw0 = blockIdx.x * 32, o0 = blockIdx.y * 32;
  const int tid = threadIdx.x;
  {
    const int hwl = tid >> 3, ol = (tid & 7) * 4;
    f32x4 v = *(const f32x4*)&o2[(size_t)(b * HW + hw0 + hwl) * CH + o0 + ol];
#pragma unroll
    for (int i = 0; i < 4; ++i) t[ol + i][hwl] = v[i];
  }
  __syncthreads();
  const int ol = tid >> 3, hwl = (tid & 7) * 4;
  const int ch = o0 + ol;
  const float s = sc[ch], bb = bi[ch];
  const size_t xi = (size_t)(b * CH + ch) * HW + hw0 + hwl;
  f32x4 xv = *(const f32x4*)&x[xi];
  f32x4 r;
#pragma unroll
  for (int i = 0; i < 4; ++i) {
    float v = t[ol][hwl + i] * s + bb + xv[i];
    r[i] = v > 0.f ? v : 0.f;
  }
  *(f32x4*)&out[xi] = r;
}

// ---------------- workspace layout (bytes) ----------------
#define WS_XN 0ULL            // xn NHWC bf16:        6,422,528
#define WS_W1T 6422528ULL     // w1t bf16:            1,179,648
#define WS_W2T 7602176ULL     // w2t bf16:            1,179,648
#define WS_WOF 8781824ULL     // wof bf16 pad64:        294,912
#define WS_OFFB 9076736ULL    // offb f32 [m][18]:      903,168
#define WS_A1 9979904ULL      // A1 bf16 [m][2304]:  57,802,752
#define WS_OBUF 67782656ULL   // o1/o2 f32 (shared): 12,845,056
#define WS_ACT 80627712ULL    // act bf16 NHWC:       6,422,528
#define WS_ZP 87050240ULL     // zero page:               4,096
#define WS_STAT 87054336ULL   // s1,sq1,s2,sq2:           4,096
#define WS_SCB 87058432ULL    // sc1,bi1,sc2,bi2:         4,096
// total: 87,062,528 (same footprint as round 5)

extern "C" void kernel_launch(void* const* d_in, const int* in_sizes, int n_in,
                              void* d_out, int out_size, void* d_ws, size_t ws_size,
                              hipStream_t stream) {
  const float* x = (const float*)d_in[0];
  const float* w_off = (const float*)d_in[1];
  const float* b_off = (const float*)d_in[2];
  const float* w1 = (const float*)d_in[3];
  const float* g1 = (const float*)d_in[4];
  const float* be1 = (const float*)d_in[5];
  const float* w2 = (const float*)d_in[6];
  const float* g2 = (const float*)d_in[7];
  const float* be2 = (const float*)d_in[8];
  float* out = (float*)d_out;
  char* ws = (char*)d_ws;

  bf16* xn = (bf16*)(ws + WS_XN);
  bf16* w1t = (bf16*)(ws + WS_W1T);
  bf16* w2t = (bf16*)(ws + WS_W2T);
  bf16* wof = (bf16*)(ws + WS_WOF);
  float* offb = (float*)(ws + WS_OFFB);
  bf16* A1 = (bf16*)(ws + WS_A1);
  float* obuf = (float*)(ws + WS_OBUF);
  bf16* act = (bf16*)(ws + WS_ACT);
  bf16* zp = (bf16*)(ws + WS_ZP);
  float* s1 = (float*)(ws + WS_STAT);
  float* sq1 = (float*)(ws + WS_STAT + 1024);
  float* s2 = (float*)(ws + WS_STAT + 2048);
  float* sq2 = (float*)(ws + WS_STAT + 3072);
  float* sc1 = (float*)(ws + WS_SCB);
  float* bi1 = (float*)(ws + WS_SCB + 1024);
  float* sc2 = (float*)(ws + WS_SCB + 2048);
  float* bi2 = (float*)(ws + WS_SCB + 3072);

  hipMemsetAsync(ws + WS_ZP, 0, 8192, stream);      // zp + stats
  hipMemsetAsync(ws + WS_OFFB, 0, 903168, stream);  // offset split-K accum
  hipMemsetAsync(ws + WS_OBUF, 0, 12845056, stream);

  nchw2nhwc_k<<<dim3(98, 8, 4), 256, 0, stream>>>(x, xn);
  reorder_w_k<<<2304, 256, 0, stream>>>(w1, w1t, 256, 256);
  reorder_w_k<<<2304, 256, 0, stream>>>(w2, w2t, 256, 256);
  reorder_w_k<<<576, 256, 0, stream>>>(w_off, wof, 18, 64);

  // offset conv: implicit im2col (dil2,pad2), split-K=4 -> offb
  offset_gemm_k<<<dim3(1, 196, 4), 256, 0, stream>>>(xn, wof, zp, offb);

  // deform sample -> A1
  build_deform_k<<<392, 256, 0, stream>>>(xn, offb, b_off, A1);

  // deform GEMM: linear A1, 128x128 tile, split-K=3 -> obuf f32
  gemm128_k<0><<<dim3(2, 98, 3), 256, 0, stream>>>(A1, w1t, zp, obuf, 0, 0);

  stats_f32<<<196, 256, 0, stream>>>(obuf, s1, sq1);
  affine_k<<<1, 256, 0, stream>>>(s1, sq1, g1, be1, sc1, bi1);
  a1_f32<<<1568, 256, 0, stream>>>(obuf, sc1, bi1, act);

  // conv2: implicit im2col (dil1,pad1), 128x128 tile, split-K=3 -> obuf f32
  hipMemsetAsync(ws + WS_OBUF, 0, 12845056, stream);
  gemm128_k<1><<<dim3(2, 98, 3), 256, 0, stream>>>(act, w2t, zp, obuf, 1, 1);

  stats_f32<<<196, 256, 0, stream>>>(obuf, s2, sq2);
  affine_k<<<1, 256, 0, stream>>>(s2, sq2, g2, be2, sc2, bi2);

  final_f32<<<dim3(98, 8, 4), 256, 0, stream>>>(obuf, x, sc2, bi2, out);
}

// Round 7
// 215.863 us; speedup vs baseline: 1.3206x; 1.3206x over previous
//
#include <hip/hip_runtime.h>

typedef __bf16 bf16;
typedef bf16 bf16x4 __attribute__((ext_vector_type(4)));
typedef bf16 bf16x8 __attribute__((ext_vector_type(8)));
typedef float f32x4 __attribute__((ext_vector_type(4)));

#define CH 256
#define HH 56
#define WW 56
#define HW 3136
#define MM 12544
#define KT 2304

__device__ __forceinline__ void gll16(const bf16* g, bf16* l) {
  __builtin_amdgcn_global_load_lds(
      (const __attribute__((address_space(1))) void*)g,
      (__attribute__((address_space(3))) void*)l, 16, 0, 0);
}

// ---------------- NCHW fp32 -> NHWC bf16 ----------------
__global__ __launch_bounds__(256) void nchw2nhwc_k(const float* __restrict__ x,
                                                   bf16* __restrict__ o) {
  __shared__ float t[32][33];
  const int b = blockIdx.z, hw0 = blockIdx.x * 32, c0 = blockIdx.y * 32;
  const int tid = threadIdx.x;
  {
    const int cl = tid >> 3, hwl = (tid & 7) * 4;
    f32x4 v = *(const f32x4*)&x[(size_t)(b * CH + c0 + cl) * HW + hw0 + hwl];
#pragma unroll
    for (int i = 0; i < 4; ++i) t[cl][hwl + i] = v[i];
  }
  __syncthreads();
  const int hwl = tid >> 3, cl = (tid & 7) * 4;
  bf16x4 ov;
#pragma unroll
  for (int i = 0; i < 4; ++i) ov[i] = (bf16)t[cl + i][hwl];
  *(bf16x4*)&o[(size_t)(b * HW + hw0 + hwl) * CH + c0 + cl] = ov;
}

// ---------------- weight reorder: [O][C][3][3] fp32 -> [Ntot][tap*256+c] bf16
__global__ void reorder_w_k(const float* __restrict__ in, bf16* __restrict__ out,
                            int Nsrc, int Ntot) {
  const int idx = blockIdx.x * 256 + threadIdx.x;
  if (idx >= Ntot * KT) return;
  const int o = idx / KT, r = idx - o * KT;
  const int k = r >> 8, c = r & 255;
  float v = (o < Nsrc) ? in[(size_t)(o * CH + c) * 9 + k] : 0.f;
  out[idx] = (bf16)v;
}

// ---------------- deform sample: contiguous-line writes, bias added here ------
__global__ __launch_bounds__(256) void build_deform_k(
    const bf16* __restrict__ xn, const float* __restrict__ offb,
    const float* __restrict__ boff, bf16* __restrict__ A1) {
  const int tid = threadIdx.x;
  const int m = blockIdx.x * 32 + (tid >> 3);
  const int l7 = tid & 7;
  const int b = m / HW, hw = m - b * HW;
  const int h = hw / WW, w = hw - h * WW;
  const float* orow = offb + m * 18;
  const bf16* xb = xn + (size_t)b * HW * CH;
  bf16* dst = A1 + (size_t)m * KT;
  for (int tap = 0; tap < 9; ++tap) {
    const int ky = tap / 3, kx = tap - ky * 3;
    const float dy = orow[2 * tap] + boff[2 * tap];
    const float dx = orow[2 * tap + 1] + boff[2 * tap + 1];
    const float py = (float)(h + ky * 2 - 2) + dy;
    const float px = (float)(w + kx * 2 - 2) + dx;
    const float y0f = floorf(py), x0f = floorf(px);
    const int y0 = (int)y0f, x0 = (int)x0f;
    const float wy = py - y0f, wx = px - x0f;
    const float w00 = (1.f - wy) * (1.f - wx), w01 = (1.f - wy) * wx;
    const float w10 = wy * (1.f - wx), w11 = wy * wx;
    const bool vy0 = (unsigned)y0 < HH, vy1 = (unsigned)(y0 + 1) < HH;
    const bool vx0 = (unsigned)x0 < WW, vx1 = (unsigned)(x0 + 1) < WW;
    const bf16* p00 = xb + (long long)(y0 * WW + x0) * CH;
#pragma unroll
    for (int j = 0; j < 4; ++j) {
      const int cc = j * 64 + l7 * 8;  // lanes 0..7 -> contiguous 128B line
      bf16x8 v00 = {}, v01 = {}, v10 = {}, v11 = {};
      if (vy0 && vx0) v00 = *(const bf16x8*)(p00 + cc);
      if (vy0 && vx1) v01 = *(const bf16x8*)(p00 + CH + cc);
      if (vy1 && vx0) v10 = *(const bf16x8*)(p00 + WW * CH + cc);
      if (vy1 && vx1) v11 = *(const bf16x8*)(p00 + WW * CH + CH + cc);
      bf16x8 o;
#pragma unroll
      for (int i = 0; i < 8; ++i)
        o[i] = (bf16)(w00 * (float)v00[i] + w01 * (float)v01[i] +
                      w10 * (float)v10[i] + w11 * (float)v11[i]);
      *(bf16x8*)(dst + tap * 256 + cc) = o;
    }
  }
}

// ---------------- 64x64 GEMM tile, dbuf gll16 + COUNTED vmcnt, XOR swizzle ----
// MODE 0: A linear k-major [m][KT].  MODE 1: A implicit im2col from NHWC bf16.
// EPI 1: bf16 store [m][256] + fused BN stats.  EPI 0: atomic 18-col offset epi.
// SWZ 1: flat 784-block grid, XCD-chunked, n-fastest (4 n-blocks of one A-panel
//        land on one XCD -> A L2-fill once).
template <int MODE, int EPI, int SWZ>
__global__ __launch_bounds__(256, 3) void gemm_k(
    const bf16* __restrict__ Asrc, const bf16* __restrict__ Bt,
    const bf16* __restrict__ zp, bf16* __restrict__ outb,
    float* __restrict__ sS, float* __restrict__ sQ,
    float* __restrict__ offout, const int ksteps, const int dil, const int pad) {
  __shared__ __align__(16) bf16 Ab[2][4096];
  __shared__ __align__(16) bf16 Bb[2][4096];
  const int tid = threadIdx.x;
  int n0, m0;
  if (SWZ) {
    const int gid = blockIdx.x;               // 784 = 8 XCDs x 98
    const int swz = (gid & 7) * 98 + (gid >> 3);
    n0 = (swz & 3) * 64;
    m0 = (swz >> 2) * 64;
  } else {
    n0 = blockIdx.x * 64;
    m0 = blockIdx.y * 64;
  }
  const int kbase = blockIdx.z * ksteps * 64;
  const int lane = tid & 63, wv = tid >> 6;
  const int wrM = wv >> 1, wcN = wv & 1;
  const int fr = lane & 15, kg = lane >> 4;
  const int srow = tid >> 3, cpos = tid & 7;
  const int sxor = (cpos ^ (srow & 7)) * 8;  // source-side swizzle (involution)

  int bb[2], hh[2], wwv[2];
  const bf16* aptr[2];
  if (MODE == 1) {
#pragma unroll
    for (int pa = 0; pa < 2; ++pa) {
      const int m = m0 + pa * 32 + srow;
      bb[pa] = m / HW;
      const int hw = m - bb[pa] * HW;
      hh[pa] = hw / WW;
      wwv[pa] = hw - hh[pa] * WW;
    }
  } else {
#pragma unroll
    for (int pa = 0; pa < 2; ++pa)
      aptr[pa] = Asrc + (size_t)(m0 + pa * 32 + srow) * KT + kbase + sxor;
  }
  const bf16* bptr[2];
#pragma unroll
  for (int pb = 0; pb < 2; ++pb)
    bptr[pb] = Bt + (size_t)(n0 + pb * 32 + srow) * KT + kbase + sxor;

  f32x4 acc[2][2] = {};

  auto STAGE = [&](int kt, int buf) {   // 4 gll16 per thread
    const int kk = kbase + kt * 64;
#pragma unroll
    for (int pa = 0; pa < 2; ++pa) {
      const bf16* as;
      if (MODE == 0) {
        as = aptr[pa] + kt * 64;
      } else {
        const int tap = kk >> 8, coff = kk & 255;
        const int ky = tap / 3, kx = tap - ky * 3;
        const int y = hh[pa] + ky * dil - pad, xx = wwv[pa] + kx * dil - pad;
        const bool ok = ((unsigned)y < HH) && ((unsigned)xx < WW);
        as = ok ? Asrc + ((size_t)(bb[pa] * HW + y * WW + xx) * CH + coff + sxor)
                : zp + sxor;
      }
      gll16(as, &Ab[buf][(pa * 32 + srow) * 64 + cpos * 8]);
    }
#pragma unroll
    for (int pb = 0; pb < 2; ++pb)
      gll16(bptr[pb] + kt * 64, &Bb[buf][(pb * 32 + srow) * 64 + cpos * 8]);
  };

  auto COMPUTE = [&](int buf) {
#pragma unroll
    for (int kh = 0; kh < 2; ++kh) {
      bf16x8 af[2], bv[2];
#pragma unroll
      for (int mf = 0; mf < 2; ++mf) {
        const int row = wrM * 32 + mf * 16 + fr;
        const int g = (kh * 4 + kg) ^ (row & 7);
        af[mf] = *(const bf16x8*)&Ab[buf][row * 64 + g * 8];
      }
#pragma unroll
      for (int nf = 0; nf < 2; ++nf) {
        const int row = wcN * 32 + nf * 16 + fr;
        const int g = (kh * 4 + kg) ^ (row & 7);
        bv[nf] = *(const bf16x8*)&Bb[buf][row * 64 + g * 8];
      }
#pragma unroll
      for (int mf = 0; mf < 2; ++mf)
#pragma unroll
        for (int nf = 0; nf < 2; ++nf)
          acc[mf][nf] = __builtin_amdgcn_mfma_f32_16x16x32_bf16(af[mf], bv[nf],
                                                                acc[mf][nf], 0, 0, 0);
    }
  };

  // depth-2 pipeline, counted vmcnt (T4): batch for tile k issued at bottom of
  // iter k-2, waited at top of iter k -> one full K-step of latency coverage.
  STAGE(0, 0);
  STAGE(1, 1);
  int buf = 0;
  for (int kt = 0; kt < ksteps; ++kt) {
    if (kt + 1 < ksteps) {
      asm volatile("s_waitcnt vmcnt(4)" ::: "memory");  // oldest batch landed
    } else {
      asm volatile("s_waitcnt vmcnt(0)" ::: "memory");  // last tile: drain
    }
    __builtin_amdgcn_s_barrier();
    __builtin_amdgcn_sched_barrier(0);
    COMPUTE(buf);
    __builtin_amdgcn_sched_barrier(0);
    __builtin_amdgcn_s_barrier();
    if (kt + 2 < ksteps) STAGE(kt + 2, buf);  // safe: buf consumed by all waves
    buf ^= 1;
  }

  if (EPI == 1) {
    // direct bf16 store
#pragma unroll
    for (int mf = 0; mf < 2; ++mf) {
      const int rr = m0 + wrM * 32 + mf * 16 + kg * 4;
#pragma unroll
      for (int nf = 0; nf < 2; ++nf) {
        const int col = n0 + wcN * 32 + nf * 16 + fr;
#pragma unroll
        for (int r = 0; r < 4; ++r)
          outb[(size_t)(rr + r) * CH + col] = (bf16)acc[mf][nf][r];
      }
    }
    // fused BN stats: per-thread partial -> kg-shuffle -> LDS -> global atomics
    float ps[2], pq[2];
#pragma unroll
    for (int nf = 0; nf < 2; ++nf) {
      float s = 0.f, q = 0.f;
#pragma unroll
      for (int mf = 0; mf < 2; ++mf)
#pragma unroll
        for (int r = 0; r < 4; ++r) {
          const float v = acc[mf][nf][r];
          s += v;
          q += v * v;
        }
      s += __shfl_xor(s, 16);
      s += __shfl_xor(s, 32);
      q += __shfl_xor(q, 16);
      q += __shfl_xor(q, 32);
      ps[nf] = s;
      pq[nf] = q;
    }
    float* red = (float*)&Ab[0][0];  // 128 floats scratch (K-loop done)
    if (tid < 128) red[tid] = 0.f;
    __syncthreads();
    if (kg == 0) {
#pragma unroll
      for (int nf = 0; nf < 2; ++nf) {
        const int cb = wcN * 32 + nf * 16 + fr;
        atomicAdd(&red[cb], ps[nf]);
        atomicAdd(&red[64 + cb], pq[nf]);
      }
    }
    __syncthreads();
    if (tid < 64) {
      atomicAdd(&sS[n0 + tid], red[tid]);
      atomicAdd(&sQ[n0 + tid], red[64 + tid]);
    }
  } else {
    // split-K offset epilogue
#pragma unroll
    for (int mf = 0; mf < 2; ++mf) {
      const int rr = m0 + wrM * 32 + mf * 16 + kg * 4;
#pragma unroll
      for (int nf = 0; nf < 2; ++nf) {
        const int col = n0 + wcN * 32 + nf * 16 + fr;
        if (col < 18) {
#pragma unroll
          for (int r = 0; r < 4; ++r)
            atomicAdd(&offout[(size_t)(rr + r) * 18 + col], acc[mf][nf][r]);
        }
      }
    }
  }
}

__global__ void affine_k(const float* __restrict__ s, const float* __restrict__ sq,
                         const float* __restrict__ g, const float* __restrict__ be,
                         float* __restrict__ sc, float* __restrict__ bi) {
  const int c = threadIdx.x;
  const float inv = 1.f / (float)MM;
  const float mean = s[c] * inv;
  const float var = sq[c] * inv - mean * mean;
  const float scale = g[c] * rsqrtf(var + 1e-5f);
  sc[c] = scale;
  bi[c] = be[c] - mean * scale;
}

// ---------------- act = bf16(relu(in*scale+bias)), bf16 in/out
__global__ __launch_bounds__(256) void a1_kb(const bf16* __restrict__ in,
                                             const float* __restrict__ sc,
                                             const float* __restrict__ bi,
                                             bf16* __restrict__ out) {
  const size_t idx = (size_t)(blockIdx.x * 256 + threadIdx.x) * 8;
  const int c0 = (int)(idx & 255);
  bf16x8 v = *(const bf16x8*)&in[idx];
  bf16x8 o;
#pragma unroll
  for (int i = 0; i < 8; ++i) {
    float r = (float)v[i] * sc[c0 + i] + bi[c0 + i];
    o[i] = (bf16)(r > 0.f ? r : 0.f);
  }
  *(bf16x8*)&out[idx] = o;
}

// ---------------- out = relu(o2*sc+bi + x), bf16 NHWC -> f32 NCHW
__global__ __launch_bounds__(256) void final_kb(const bf16* __restrict__ o2,
                                                const float* __restrict__ x,
                                                const float* __restrict__ sc,
                                                const float* __restrict__ bi,
                                                float* __restrict__ out) {
  __shared__ float t[32][33];
  const int b = blockIdx.z, hw0 = blockIdx.x * 32, o0 = blockIdx.y * 32;
  const int tid = threadIdx.x;
  {
    const int hwl = tid >> 3, ol = (tid & 7) * 4;
    bf16x4 v = *(const bf16x4*)&o2[(size_t)(b * HW + hw0 + hwl) * CH + o0 + ol];
#pragma unroll
    for (int i = 0; i < 4; ++i) t[ol + i][hwl] = (float)v[i];
  }
  __syncthreads();
  const int ol = tid >> 3, hwl = (tid & 7) * 4;
  const int ch = o0 + ol;
  const float s = sc[ch], bb = bi[ch];
  const size_t xi = (size_t)(b * CH + ch) * HW + hw0 + hwl;
  f32x4 xv = *(const f32x4*)&x[xi];
  f32x4 r;
#pragma unroll
  for (int i = 0; i < 4; ++i) {
    float v = t[ol][hwl + i] * s + bb + xv[i];
    r[i] = v > 0.f ? v : 0.f;
  }
  *(f32x4*)&out[xi] = r;
}

// ---------------- workspace layout (bytes) ----------------
#define WS_XN 0ULL            // xn NHWC bf16:        6,422,528
#define WS_W1T 6422528ULL     // w1t bf16:            1,179,648
#define WS_W2T 7602176ULL     // w2t bf16:            1,179,648
#define WS_WOF 8781824ULL     // wof bf16 pad64:        294,912
#define WS_OFFB 9076736ULL    // offb f32 [m][18]:      903,168
#define WS_A1 9979904ULL      // A1 bf16 [m][2304]:  57,802,752
#define WS_O1 67782656ULL     // out1 bf16 NHWC:      6,422,528
#define WS_ACT 74205184ULL    // act bf16 NHWC:       6,422,528
#define WS_O2 80627712ULL     // out2 bf16 NHWC:      6,422,528
#define WS_ZP 87050240ULL     // zero page:               4,096
#define WS_STAT 87054336ULL   // s1,sq1,s2,sq2:           4,096
#define WS_SCB 87058432ULL    // sc1,bi1,sc2,bi2:         4,096
// total: 87,062,528

extern "C" void kernel_launch(void* const* d_in, const int* in_sizes, int n_in,
                              void* d_out, int out_size, void* d_ws, size_t ws_size,
                              hipStream_t stream) {
  const float* x = (const float*)d_in[0];
  const float* w_off = (const float*)d_in[1];
  const float* b_off = (const float*)d_in[2];
  const float* w1 = (const float*)d_in[3];
  const float* g1 = (const float*)d_in[4];
  const float* be1 = (const float*)d_in[5];
  const float* w2 = (const float*)d_in[6];
  const float* g2 = (const float*)d_in[7];
  const float* be2 = (const float*)d_in[8];
  float* out = (float*)d_out;
  char* ws = (char*)d_ws;

  bf16* xn = (bf16*)(ws + WS_XN);
  bf16* w1t = (bf16*)(ws + WS_W1T);
  bf16* w2t = (bf16*)(ws + WS_W2T);
  bf16* wof = (bf16*)(ws + WS_WOF);
  float* offb = (float*)(ws + WS_OFFB);
  bf16* A1 = (bf16*)(ws + WS_A1);
  bf16* o1 = (bf16*)(ws + WS_O1);
  bf16* act = (bf16*)(ws + WS_ACT);
  bf16* o2 = (bf16*)(ws + WS_O2);
  bf16* zp = (bf16*)(ws + WS_ZP);
  float* s1 = (float*)(ws + WS_STAT);
  float* sq1 = (float*)(ws + WS_STAT + 1024);
  float* s2 = (float*)(ws + WS_STAT + 2048);
  float* sq2 = (float*)(ws + WS_STAT + 3072);
  float* sc1 = (float*)(ws + WS_SCB);
  float* bi1 = (float*)(ws + WS_SCB + 1024);
  float* sc2 = (float*)(ws + WS_SCB + 2048);
  float* bi2 = (float*)(ws + WS_SCB + 3072);

  hipMemsetAsync(ws + WS_ZP, 0, 8192, stream);      // zp + stats
  hipMemsetAsync(ws + WS_OFFB, 0, 903168, stream);  // offset split-K accum

  nchw2nhwc_k<<<dim3(98, 8, 4), 256, 0, stream>>>(x, xn);
  reorder_w_k<<<2304, 256, 0, stream>>>(w1, w1t, 256, 256);
  reorder_w_k<<<2304, 256, 0, stream>>>(w2, w2t, 256, 256);
  reorder_w_k<<<576, 256, 0, stream>>>(w_off, wof, 18, 64);

  // offset conv: implicit im2col (dil2,pad2), split-K=4 -> offb
  gemm_k<1, 0, 0><<<dim3(1, 196, 4), 256, 0, stream>>>(
      xn, wof, zp, nullptr, nullptr, nullptr, offb, 9, 2, 2);

  // deform sample -> A1
  build_deform_k<<<392, 256, 0, stream>>>(xn, offb, b_off, A1);

  // deform GEMM: linear A1, full-K, XCD-swizzled flat grid -> o1 bf16 (+stats)
  gemm_k<0, 1, 1><<<dim3(784), 256, 0, stream>>>(A1, w1t, zp, o1, s1, sq1,
                                                 nullptr, 36, 0, 0);
  affine_k<<<1, 256, 0, stream>>>(s1, sq1, g1, be1, sc1, bi1);
  a1_kb<<<1568, 256, 0, stream>>>(o1, sc1, bi1, act);

  // conv2: implicit im2col (dil1,pad1), full-K, XCD-swizzled -> o2 bf16 (+stats)
  gemm_k<1, 1, 1><<<dim3(784), 256, 0, stream>>>(act, w2t, zp, o2, s2, sq2,
                                                 nullptr, 36, 1, 1);
  affine_k<<<1, 256, 0, stream>>>(s2, sq2, g2, be2, sc2, bi2);

  final_kb<<<dim3(98, 8, 4), 256, 0, stream>>>(o2, x, sc2, bi2, out);
}